// Round 3
// baseline (275.901 us; speedup 1.0000x reference)
//
#include <hip/hip_runtime.h>
#include <hip/hip_bf16.h>
#include <math.h>

// Problem constants (from reference module)
#define LENGTH_MIN 5
#define LENGTH_MAX 64
#define EMBED_DIM 512
#define HDIM      256
#define POOL      20
#define TOPK      5
#define BETA      0.5f
#define LN_EPS    1e-5f
#define COS_EPS   1e-8f

typedef float v4f __attribute__((ext_vector_type(4)));

// ws layout (floats):
//   [32 + b*32 + p]        dense weights Wd[b][p], p<20 (stride 32 for alignment)
//   [32 + 32*B + b]        len[b] (int)

// Fused kernel: per-block redundant prep (quality mean, w1/b1 LN stats in
// closed form, key inverse norms) + query projection + cosine sims + softmax
// + top-5 -> DENSE weight row + dynamic length. 4 batches/block, 256 threads.
__global__ __launch_bounds__(256) void query_all_kernel(
    const float* __restrict__ quality, const float* __restrict__ keys,
    const float* __restrict__ w1, const float* __restrict__ b1,
    const float* __restrict__ ln_g, const float* __restrict__ ln_b,
    const float* __restrict__ w2, const float* __restrict__ b2,
    float* __restrict__ ws, int B)
{
    __shared__ float red[24];          // 6 reduction values x 4 waves
    __shared__ float invk_s[POOL];
    __shared__ float hn_s[4][HDIM];
    __shared__ float qbuf[4][EMBED_DIM];

    int t = threadIdx.x;
    int wave = t >> 6, lane = t & 63;
    int b0 = blockIdx.x * 4;

    // ---- redundant prep: 6 block-reductions batched into ONE __syncthreads ----
    float qpart = 0.f;
    for (int i = t; i < B; i += 256) qpart += quality[i];
    float a = w1[t], c = b1[t];        // HDIM == 256 == blockDim
    float vals[6] = { qpart, a, a * a, c, c * c, a * c };
    #pragma unroll
    for (int i = 0; i < 6; i++) {
        float v = vals[i];
        #pragma unroll
        for (int off = 32; off > 0; off >>= 1) v += __shfl_xor(v, off);
        if (lane == 0) red[i * 4 + wave] = v;
    }
    // key inverse norms: wave w handles keys {w, w+4, ..., w+16}
    #pragma unroll
    for (int j = 0; j < 5; j++) {
        int p = wave + 4 * j;
        const float* kp = keys + p * EMBED_DIM;
        float s = 0.f;
        #pragma unroll
        for (int i = 0; i < 8; i++) { float x = kp[lane + 64 * i]; s = fmaf(x, x, s); }
        #pragma unroll
        for (int off = 32; off > 0; off >>= 1) s += __shfl_xor(s, off);
        if (lane == 0) invk_s[p] = 1.f / fmaxf(sqrtf(s), COS_EPS);
    }
    __syncthreads();

    float qmean = (red[0] + red[1] + red[2] + red[3]) / (float)B;
    float mw1   = (red[4] + red[5] + red[6] + red[7]) * (1.f / 256.f);
    float Ew2   = (red[8] + red[9] + red[10] + red[11]) * (1.f / 256.f);
    float mb1   = (red[12] + red[13] + red[14] + red[15]) * (1.f / 256.f);
    float Eb2   = (red[16] + red[17] + red[18] + red[19]) * (1.f / 256.f);
    float Eab   = (red[20] + red[21] + red[22] + red[23]) * (1.f / 256.f);
    float Vw1 = Ew2 - mw1 * mw1;
    float Vb1 = Eb2 - mb1 * mb1;
    float Cv  = Eab - mw1 * mb1;

    // ---- LN(q*w1+b1) -> relu, closed-form stats (quadratic in scalar q) ----
    float gt = ln_g[t], lbt = ln_b[t];
    float qv4[4];
    #pragma unroll
    for (int bi = 0; bi < 4; bi++) {
        float q = quality[b0 + bi];
        qv4[bi] = q;
        float mu  = q * mw1 + mb1;
        float var = q * q * Vw1 + 2.f * q * Cv + Vb1;
        float inv = rsqrtf(var + LN_EPS);
        float h = q * a + c;
        hn_s[bi][t] = fmaxf((h - mu) * inv * gt + lbt, 0.f);
    }
    __syncthreads();

    // ---- query = hn @ w2 + b2 : thread t -> columns 2t, 2t+1, 4 batches ----
    int d0 = 2 * t;
    float2 b2v = *(const float2*)(b2 + d0);
    float acc0[4], acc1[4];
    #pragma unroll
    for (int bi = 0; bi < 4; bi++) { acc0[bi] = b2v.x; acc1[bi] = b2v.y; }

    for (int j = 0; j < HDIM; j += 4) {
        float2 wv0 = *(const float2*)(w2 + (j + 0) * EMBED_DIM + d0);
        float2 wv1 = *(const float2*)(w2 + (j + 1) * EMBED_DIM + d0);
        float2 wv2 = *(const float2*)(w2 + (j + 2) * EMBED_DIM + d0);
        float2 wv3 = *(const float2*)(w2 + (j + 3) * EMBED_DIM + d0);
        #pragma unroll
        for (int bi = 0; bi < 4; bi++) {
            float4 hv = *(const float4*)&hn_s[bi][j];
            acc0[bi] = fmaf(hv.x, wv0.x, acc0[bi]);
            acc1[bi] = fmaf(hv.x, wv0.y, acc1[bi]);
            acc0[bi] = fmaf(hv.y, wv1.x, acc0[bi]);
            acc1[bi] = fmaf(hv.y, wv1.y, acc1[bi]);
            acc0[bi] = fmaf(hv.z, wv2.x, acc0[bi]);
            acc1[bi] = fmaf(hv.z, wv2.y, acc1[bi]);
            acc0[bi] = fmaf(hv.w, wv3.x, acc0[bi]);
            acc1[bi] = fmaf(hv.w, wv3.y, acc1[bi]);
        }
    }
    #pragma unroll
    for (int bi = 0; bi < 4; bi++)
        *(float2*)&qbuf[bi][d0] = make_float2(acc0[bi], acc1[bi]);
    __syncthreads();

    // ---- one wave per batch: norm, sims, softmax, top-5, length ----
    int bi = wave;
    float s[POOL + 1];
    #pragma unroll
    for (int p = 0; p <= POOL; p++) s[p] = 0.f;
    #pragma unroll
    for (int i = 0; i < 8; i++) {
        int d = lane + 64 * i;
        float qd = qbuf[bi][d];
        s[POOL] = fmaf(qd, qd, s[POOL]);
        #pragma unroll
        for (int p = 0; p < POOL; p++)
            s[p] = fmaf(qd, keys[p * EMBED_DIM + d], s[p]);
    }
    #pragma unroll
    for (int off = 32; off > 0; off >>= 1) {
        #pragma unroll
        for (int p = 0; p <= POOL; p++) s[p] += __shfl_xor(s[p], off);
    }

    float invq  = 1.f / fmaxf(sqrtf(s[POOL]), COS_EPS);
    float scale = 1.f + BETA * qmean;
    float sim[POOL];
    #pragma unroll
    for (int p = 0; p < POOL; p++) sim[p] = s[p] * invq * invk_s[p] * scale;

    float m = sim[0];
    #pragma unroll
    for (int p = 1; p < POOL; p++) m = fmaxf(m, sim[p]);
    float e[POOL]; float den = 0.f;
    #pragma unroll
    for (int p = 0; p < POOL; p++) { e[p] = expf(sim[p] - m); den += e[p]; }
    float invden = 1.f / den;

    // top-5 selection (only membership matters; weights = e[p]*invden)
    unsigned picked = 0;
    #pragma unroll
    for (int k = 0; k < TOPK; k++) {
        float best = -1.f; int bidx = 0;
        #pragma unroll
        for (int p = 0; p < POOL; p++) {
            bool free_p = ((picked >> p) & 1u) == 0u;
            if (free_p && e[p] > best) { best = e[p]; bidx = p; }
        }
        picked |= (1u << bidx);
    }

    if (lane == 0) {
        int b = b0 + bi;
        float* Wd   = ws + 32;
        int*   lenp = (int*)(ws + 32 + 32 * B);
        #pragma unroll
        for (int p = 0; p < POOL; p++)
            Wd[b * 32 + p] = ((picked >> p) & 1u) ? e[p] * invden : 0.f;
        // match reference fp32 op order: 5 + 59*(1 - q/5)
        float q = qv4[bi];
        float lf = __fadd_rn(5.f, __fmul_rn(59.f, __fsub_rn(1.f, __fdiv_rn(q, 5.f))));
        int len = (int)truncf(lf);
        len = min(max(len, LENGTH_MIN), LENGTH_MAX);
        lenp[b] = len;
    }
}

// Broadcast-GEMM scatter: out[b,l,:] = sum_p Wd[b,p] * pe[p,l,:], masked by len.
// Block = (one l, 64-batch chunk). 128 threads x 4 cols. Each thread holds
// pe[p, l, 4 cols] for ALL 20 p in registers (loaded once from L2), then
// streams 64 batches reading only the wave-uniform 80B weight row + len
// (scalar loads). pe L2 traffic: 40 MB total (vs 671 MB for the gather form).
// Non-temporal float4 stores keep the 134 MB output stream out of L2.
__global__ __launch_bounds__(128) void scatter_kernel(
    const float* __restrict__ pe, const float* __restrict__ ws,
    float* __restrict__ out, int B)
{
    int l     = blockIdx.x & 63;          // 0..63
    int chunk = blockIdx.x >> 6;          // B/64 chunks
    int b0    = chunk * 64;
    int d4    = threadIdx.x * 4;          // 128 threads * 4 = 512 cols

    const float* Wd   = ws + 32;
    const int*   lenp = (const int*)(ws + 32 + 32 * B);

    // preload pe slab for this l into registers: 20 x float4 = 80 VGPRs
    v4f pv[POOL];
    #pragma unroll
    for (int p = 0; p < POOL; p++)
        pv[p] = *(const v4f*)(pe + (p * 64 + l) * EMBED_DIM + d4);

    float* orow = out + (size_t)(b0 * 64 + l) * EMBED_DIM + d4;
    #pragma unroll 4
    for (int bi = 0; bi < 64; bi++) {
        int b = b0 + bi;
        float msk = (l < lenp[b]) ? 1.f : 0.f;   // uniform per iteration
        const float* wrow = Wd + b * 32;         // uniform -> scalar loads
        v4f r = { 0.f, 0.f, 0.f, 0.f };
        #pragma unroll
        for (int p = 0; p < POOL; p++)
            r += pv[p] * wrow[p];
        r *= msk;
        __builtin_nontemporal_store(r, (v4f*)orow);
        orow += (size_t)64 * EMBED_DIM;          // next batch, same l
    }
}

extern "C" void kernel_launch(void* const* d_in, const int* in_sizes, int n_in,
                              void* d_out, int out_size, void* d_ws, size_t ws_size,
                              hipStream_t stream) {
    // input order: x_embed(unused), quality, keys, prompt_embeddings,
    //              w1, b1, ln_g, ln_b, w2, b2
    const float* quality = (const float*)d_in[1];
    const float* keys    = (const float*)d_in[2];
    const float* pe      = (const float*)d_in[3];
    const float* w1      = (const float*)d_in[4];
    const float* b1      = (const float*)d_in[5];
    const float* ln_g    = (const float*)d_in[6];
    const float* ln_b    = (const float*)d_in[7];
    const float* w2      = (const float*)d_in[8];
    const float* b2      = (const float*)d_in[9];
    float* out = (float*)d_out;
    float* ws  = (float*)d_ws;
    int B = in_sizes[1];

    query_all_kernel<<<B / 4, 256, 0, stream>>>(quality, keys, w1, b1, ln_g, ln_b,
                                                w2, b2, ws, B);
    scatter_kernel<<<(B / 64) * 64, 128, 0, stream>>>(pe, ws, out, B);
}